// Round 4
// baseline (135.370 us; speedup 1.0000x reference)
//
#include <hip/hip_runtime.h>
#include <math.h>

#define BB 2
#define CC 192
#define DI 384
#define SS 16
#define RR 12
#define KK 4

// ---------------- K1: one pass over x, all three axis-mean reductions ----------------
// grid = B*C, block = 1024. seq layout: seq[i][b][pos][c]
__global__ void k_reduce(const float* __restrict__ x, float* __restrict__ seq) {
  int bc = blockIdx.x; int b = bc / CC, c = bc % CC;
  const float* base = x + (size_t)bc * 32768;
  int t = threadIdx.x;
  int w = t & 31, r = t >> 5;
  float acc = 0.f;
  __shared__ float sH[32];
  __shared__ float sMat[1024];
  if (t < 32) sH[t] = 0.f;
  __syncthreads();
  for (int h = 0; h < 32; ++h) {
    float v = base[r * 1024 + h * 32 + w];
    acc += v;
    float vv = v;
    #pragma unroll
    for (int off = 32; off > 0; off >>= 1) vv += __shfl_down(vv, off, 64);
    if ((t & 63) == 0) atomicAdd(&sH[h], vv);
  }
  sMat[t] = acc;
  float s0 = acc;
  #pragma unroll
  for (int off = 16; off > 0; off >>= 1) s0 += __shfl_down(s0, off, 32);
  if (w == 0) seq[((0 * BB + b) * 32 + r) * CC + c] = s0 * (1.f / 1024.f);
  __syncthreads();
  if (t < 32) {
    float s2 = 0.f;
    for (int rr = 0; rr < 32; ++rr) s2 += sMat[rr * 32 + t];
    seq[((2 * BB + b) * 32 + t) * CC + c] = s2 * (1.f / 1024.f);
    seq[((1 * BB + b) * 32 + t) * CC + c] = sH[t] * (1.f / 1024.f);
  }
}

// ---------------- K2: LN + in-proj(4 tokens xm + own z) + conv+silu + xp + dt, per token ----------------
// grid = 192, block = 384
__global__ void k_convall(const float* __restrict__ seq, const float* __restrict__ ln_w,
                          const float* __restrict__ ln_b, const float* __restrict__ in_w,
                          const float* __restrict__ conv_w, const float* __restrict__ conv_b,
                          const float* __restrict__ xp_w, const float* __restrict__ dt_w,
                          const float* __restrict__ dt_b, float* __restrict__ xc,
                          float* __restrict__ zbuf, float* __restrict__ dbc,
                          float* __restrict__ dtout) {
  int tok = blockIdx.x; int l = tok & 31; int tb = tok >> 5; int i = tb / BB;
  int t = threadIdx.x;
  __shared__ float sseq[4][CC];
  __shared__ float smu[4], sri[4];
  __shared__ float sxm[4][DI];
  __shared__ float xcl[DI];
  __shared__ float dbcl[44];
  // load 4 seq rows (tokens l-3..l), zero-fill out-of-range
  for (int j = t; j < 4 * CC; j += 384) {
    int k = j / CC, c = j - k * CC;
    int ls = l - 3 + k;
    sseq[k][c] = (ls >= 0) ? seq[(tb * 32 + ls) * CC + c] : 0.f;
  }
  __syncthreads();
  // LN stats: wave k handles token k
  int wid = t >> 6, lane = t & 63;
  if (wid < 4) {
    float sm = 0.f, sq = 0.f;
    for (int e = lane; e < CC; e += 64) { float v = sseq[wid][e]; sm += v; sq += v * v; }
    #pragma unroll
    for (int off = 32; off > 0; off >>= 1) { sm += __shfl_down(sm, off, 64); sq += __shfl_down(sq, off, 64); }
    if (lane == 0) { float mu = sm / CC; smu[wid] = mu; sri[wid] = rsqrtf(sq / CC - mu * mu + 1e-5f); }
  }
  __syncthreads();
  for (int j = t; j < 4 * CC; j += 384) {
    int k = j / CC, c = j - k * CC;
    sseq[k][c] = (sseq[k][c] - smu[k]) * sri[k] * ln_w[i * CC + c] + ln_b[i * CC + c];
  }
  __syncthreads();
  // in-proj: thread t = output row t; 4 tokens' xm + own token's z (weight rows reused)
  {
    const float4* wr = (const float4*)(in_w + ((size_t)i * 768 + t) * CC);
    const float4* wz = (const float4*)(in_w + ((size_t)i * 768 + 384 + t) * CC);
    const float4* s0 = (const float4*)sseq[0];
    const float4* s1 = (const float4*)sseq[1];
    const float4* s2 = (const float4*)sseq[2];
    const float4* s3 = (const float4*)sseq[3];
    float a0 = 0.f, a1 = 0.f, a2 = 0.f, a3 = 0.f, az = 0.f;
    #pragma unroll 4
    for (int c4 = 0; c4 < CC / 4; ++c4) {
      float4 w = wr[c4];
      float4 q0 = s0[c4], q1 = s1[c4], q2 = s2[c4], q3 = s3[c4];
      a0 += w.x * q0.x + w.y * q0.y + w.z * q0.z + w.w * q0.w;
      a1 += w.x * q1.x + w.y * q1.y + w.z * q1.z + w.w * q1.w;
      a2 += w.x * q2.x + w.y * q2.y + w.z * q2.z + w.w * q2.w;
      a3 += w.x * q3.x + w.y * q3.y + w.z * q3.z + w.w * q3.w;
      float4 z = wz[c4];
      az += z.x * q3.x + z.y * q3.y + z.z * q3.z + z.w * q3.w;
    }
    int bl = l - 3;
    sxm[0][t] = (bl + 0 >= 0) ? a0 : 0.f;
    sxm[1][t] = (bl + 1 >= 0) ? a1 : 0.f;
    sxm[2][t] = (bl + 2 >= 0) ? a2 : 0.f;
    sxm[3][t] = a3;
    zbuf[(size_t)tok * DI + t] = az;
  }
  __syncthreads();
  // conv K=4 + silu
  {
    int di = t;
    const float* cw = conv_w + ((size_t)i * DI + di) * KK;
    float acc = conv_b[i * DI + di];
    #pragma unroll
    for (int k = 0; k < KK; ++k) acc += cw[k] * sxm[k][di];
    acc = acc / (1.f + expf(-acc));
    xcl[di] = acc;
    xc[(size_t)tok * DI + di] = acc;
  }
  __syncthreads();
  // xp-proj: 44 outs, 8 lanes each
  if (t < 352) {
    int o = t >> 3, ln8 = t & 7;
    const float4* wr = (const float4*)(xp_w + ((size_t)i * 44 + o) * DI);
    const float4* xv = (const float4*)xcl;
    float acc = 0.f;
    #pragma unroll
    for (int c4 = ln8 * 12; c4 < ln8 * 12 + 12; ++c4) {
      float4 a = wr[c4], bq = xv[c4];
      acc += a.x * bq.x + a.y * bq.y + a.z * bq.z + a.w * bq.w;
    }
    #pragma unroll
    for (int off = 4; off > 0; off >>= 1) acc += __shfl_xor(acc, off, 8);
    if (ln8 == 0) { dbcl[o] = acc; dbc[tok * 44 + o] = acc; }
  }
  __syncthreads();
  // dt-proj + softplus
  {
    int di = t;
    const float* wr = dt_w + ((size_t)i * DI + di) * RR;
    float acc = dt_b[i * DI + di];
    #pragma unroll
    for (int r = 0; r < RR; ++r) acc += wr[r] * dbcl[r];
    float sp = (acc > 20.f) ? acc : log1pf(expf(acc));
    dtout[(size_t)tok * DI + di] = sp;
  }
}

// ---------------- K3: scan, shuffle-free serial loop; LDS partials + cooperative reduce ----------------
// grid = 288 (6 ib x 48 chunks), block = 128 (8 di x 16 s)
__global__ void k_scan(const float* __restrict__ dbc, const float* __restrict__ dtin,
                       const float* __restrict__ xc, const float* __restrict__ zbuf,
                       const float* __restrict__ A_log, const float* __restrict__ Dskip,
                       float* __restrict__ y, float* __restrict__ ymean) {
  int ib = blockIdx.x / 48;
  int di0 = (blockIdx.x % 48) * 8;
  int i = ib / BB;
  int t = threadIdx.x;
  int g = t >> 4, s = t & 15;
  int di = di0 + g;
  __shared__ float sdt[32][8], sxc[32][8], sz[32][8];
  __shared__ float sB[32][SS], sC[32][SS];
  __shared__ float spp[32 * 136];   // [l][g*17+s] padded
  __shared__ float sy[32][8];
  __shared__ float sDsk[8];
  #pragma unroll
  for (int j = t; j < 256; j += 128) {
    int l = j >> 3, gg = j & 7;
    int tok = ib * 32 + l;
    sdt[l][gg] = dtin[(size_t)tok * DI + di0 + gg];
    sxc[l][gg] = xc[(size_t)tok * DI + di0 + gg];
    sz[l][gg]  = zbuf[(size_t)tok * DI + di0 + gg];
  }
  #pragma unroll
  for (int j = t; j < 512; j += 128) {
    int l = j >> 4, ss = j & 15;
    sB[l][ss] = dbc[(ib * 32 + l) * 44 + RR + ss];
    sC[l][ss] = dbc[(ib * 32 + l) * 44 + RR + SS + ss];
  }
  if (t < 8) sDsk[t] = Dskip[i * DI + di0 + t];
  float A = -expf(A_log[((size_t)i * DI + di) * SS + s]);
  float h = 0.f;
  __syncthreads();
  #pragma unroll
  for (int l = 0; l < 32; ++l) {
    float dtt = sdt[l][g];
    h = expf(dtt * A) * h + dtt * sxc[l][g] * sB[l][s];
    spp[l * 136 + g * 17 + s] = h * sC[l][s];
  }
  __syncthreads();
  #pragma unroll
  for (int p = 0; p < 2; ++p) {
    int idx = p * 128 + t;
    int l = idx >> 3, g2 = idx & 7;
    float sum = 0.f;
    #pragma unroll
    for (int s2 = 0; s2 < 16; ++s2) sum += spp[l * 136 + g2 * 17 + s2];
    float xt = sxc[l][g2];
    float z  = sz[l][g2];
    float yv = (sum + sDsk[g2] * xt) * (z / (1.f + expf(-z)));
    y[(size_t)(ib * 32 + l) * DI + di0 + g2] = yv;
    sy[l][g2] = yv;
  }
  __syncthreads();
  if (t < 8) {
    float sum = 0.f;
    #pragma unroll
    for (int l = 0; l < 32; ++l) sum += sy[l][t];
    ymean[ib * DI + di0 + t] = sum * (1.f / 32.f);
  }
}

// ---------------- K4: out-proj + up-proj + gate (ctx from analytic Zmean via ymean) ----------------
// grid = 192, block = 384
__global__ void k_gate(const float* __restrict__ y, const float* __restrict__ ymean,
                       const float* __restrict__ out_w, const float* __restrict__ up_w,
                       const float* __restrict__ up_b, const float* __restrict__ Wg_w,
                       const float* __restrict__ Wg_b, const float* __restrict__ Ws_w,
                       const float* __restrict__ Ws_b, const float* __restrict__ Wm_w,
                       const float* __restrict__ Wm_b, const float* __restrict__ po_w,
                       float* __restrict__ P) {
  int blk = blockIdx.x; int gb = blk >> 5; int g = gb / BB, b = gb - g * BB;
  int o1 = (g == 0) ? 1 : 0, o2 = (g == 2) ? 1 : 2;
  int t = threadIdx.x;
  __shared__ float yrow[DI], ym1[DI], ym2[DI];
  __shared__ float mrow[CC], vv1[CC], vv2[CC];
  __shared__ float zrow[CC], w1[CC], w2[CC], arow[CC], ygr[CC];
  __shared__ float pa[384], pb[384], pc[384];
  yrow[t] = y[(size_t)blk * DI + t];
  ym1[t]  = ymean[(o1 * BB + b) * DI + t];
  ym2[t]  = ymean[(o2 * BB + b) * DI + t];
  __syncthreads();
  int o = (t < 192) ? t : t - 192;
  int ph = (t < 192) ? 0 : 1;
  { // stage A: three [192x384] matvecs split 2-way over input
    const float4* wg = (const float4*)(out_w + ((size_t)g  * CC + o) * DI);
    const float4* wa = (const float4*)(out_w + ((size_t)o1 * CC + o) * DI);
    const float4* wb = (const float4*)(out_w + ((size_t)o2 * CC + o) * DI);
    const float4* yv = (const float4*)yrow;
    const float4* m1 = (const float4*)ym1;
    const float4* m2 = (const float4*)ym2;
    float a0 = 0.f, a1 = 0.f, a2 = 0.f;
    #pragma unroll 4
    for (int c4 = ph * 48; c4 < ph * 48 + 48; ++c4) {
      float4 w0 = wg[c4], q0 = yv[c4];
      a0 += w0.x * q0.x + w0.y * q0.y + w0.z * q0.z + w0.w * q0.w;
      float4 wA = wa[c4], qA = m1[c4];
      a1 += wA.x * qA.x + wA.y * qA.y + wA.z * qA.z + wA.w * qA.w;
      float4 wB = wb[c4], qB = m2[c4];
      a2 += wB.x * qB.x + wB.y * qB.y + wB.z * qB.z + wB.w * qB.w;
    }
    pa[t] = a0; pb[t] = a1; pc[t] = a2;
  }
  __syncthreads();
  if (t < 192) { mrow[t] = pa[t] + pa[t + 192]; vv1[t] = pb[t] + pb[t + 192]; vv2[t] = pc[t] + pc[t + 192]; }
  __syncthreads();
  { // stage B: three [192x192] matvecs
    const float4* ug = (const float4*)(up_w + ((size_t)g  * CC + o) * CC);
    const float4* ua = (const float4*)(up_w + ((size_t)o1 * CC + o) * CC);
    const float4* ub = (const float4*)(up_w + ((size_t)o2 * CC + o) * CC);
    const float4* mv = (const float4*)mrow;
    const float4* v1 = (const float4*)vv1;
    const float4* v2 = (const float4*)vv2;
    float a0 = 0.f, a1 = 0.f, a2 = 0.f;
    #pragma unroll 4
    for (int c4 = ph * 24; c4 < ph * 24 + 24; ++c4) {
      float4 w0 = ug[c4], q0 = mv[c4];
      a0 += w0.x * q0.x + w0.y * q0.y + w0.z * q0.z + w0.w * q0.w;
      float4 wA = ua[c4], qA = v1[c4];
      a1 += wA.x * qA.x + wA.y * qA.y + wA.z * qA.z + wA.w * qA.w;
      float4 wB = ub[c4], qB = v2[c4];
      a2 += wB.x * qB.x + wB.y * qB.y + wB.z * qB.z + wB.w * qB.w;
    }
    pa[t] = a0; pb[t] = a1; pc[t] = a2;
  }
  __syncthreads();
  if (t < 192) {
    zrow[t] = up_b[g  * CC + t] + pa[t] + pa[t + 192];
    w1[t]   = up_b[o1 * CC + t] + pb[t] + pb[t + 192];
    w2[t]   = up_b[o2 * CC + t] + pc[t] + pc[t + 192];
  }
  __syncthreads();
  { // stage C: st = Ws@zrow (split-2) and ctx = Wg@[w1,w2] (ph half each)
    const float4* wr = (const float4*)(Ws_w + (size_t)o * CC);
    const float4* zv = (const float4*)zrow;
    float acc = 0.f;
    #pragma unroll 4
    for (int c4 = ph * 24; c4 < ph * 24 + 24; ++c4) {
      float4 a = wr[c4], bq = zv[c4];
      acc += a.x * bq.x + a.y * bq.y + a.z * bq.z + a.w * bq.w;
    }
    pa[t] = acc;
    const float4* gwr = (const float4*)(Wg_w + (size_t)o * 2 * CC + ph * CC);
    const float4* gmv = (const float4*)(ph == 0 ? w1 : w2);
    float acc2 = 0.f;
    #pragma unroll 4
    for (int c4 = 0; c4 < 48; ++c4) {
      float4 a = gwr[c4], bq = gmv[c4];
      acc2 += a.x * bq.x + a.y * bq.y + a.z * bq.z + a.w * bq.w;
    }
    pb[t] = acc2;
  }
  __syncthreads();
  if (t < 192) {
    float a = (Ws_b[t] + pa[t] + pa[t + 192]) + (Wg_b[t] + pb[t] + pb[t + 192]);
    arow[t] = a > 0.f ? a : 0.f;
  }
  __syncthreads();
  { // Wm stage
    const float4* mr = (const float4*)(Wm_w + (size_t)o * CC);
    const float4* av = (const float4*)arow;
    float acc = 0.f;
    #pragma unroll 4
    for (int c4 = ph * 24; c4 < ph * 24 + 24; ++c4) {
      float4 a = mr[c4], bq = av[c4];
      acc += a.x * bq.x + a.y * bq.y + a.z * bq.z + a.w * bq.w;
    }
    pa[t] = acc;
  }
  __syncthreads();
  if (t < 192) {
    float am = Wm_b[t] + pa[t] + pa[t + 192];
    am = 1.f / (1.f + expf(-am));
    ygr[t] = am * zrow[t];
  }
  __syncthreads();
  { // po stage
    const float4* pr = (const float4*)(po_w + (size_t)o * (3 * CC) + g * CC);
    const float4* yv = (const float4*)ygr;
    float acc = 0.f;
    #pragma unroll 4
    for (int c4 = ph * 24; c4 < ph * 24 + 24; ++c4) {
      float4 a = pr[c4], bq = yv[c4];
      acc += a.x * bq.x + a.y * bq.y + a.z * bq.z + a.w * bq.w;
    }
    pb[t] = acc;
  }
  __syncthreads();
  if (t < 192) P[(size_t)blk * CC + t] = pb[t] + pb[t + 192];
}

// ---------------- K5: final: warp-parallel separable stats + broadcast + residual ----------------
// grid = B*C*2, block = 256
__global__ void k_final(const float* __restrict__ x, const float* __restrict__ P,
                        const float* __restrict__ po_b, const float* __restrict__ rs_p,
                        float* __restrict__ out) {
  int bc = blockIdx.x >> 1; int half = blockIdx.x & 1;
  int b = bc / CC, c = bc % CC;
  __shared__ float p0[32], p1[32], p2[32];
  __shared__ float sbase;
  int t = threadIdx.x;
  if (t < 32) {
    float v0 = P[((0 * BB + b) * 32 + t) * CC + c];
    float v1 = P[((1 * BB + b) * 32 + t) * CC + c];
    float v2 = P[((2 * BB + b) * 32 + t) * CC + c];
    float s0 = v0, q0 = v0 * v0, s1 = v1, q1 = v1 * v1, s2 = v2, q2 = v2 * v2;
    #pragma unroll
    for (int off = 16; off > 0; off >>= 1) {
      s0 += __shfl_xor(s0, off, 32); q0 += __shfl_xor(q0, off, 32);
      s1 += __shfl_xor(s1, off, 32); q1 += __shfl_xor(q1, off, 32);
      s2 += __shfl_xor(s2, off, 32); q2 += __shfl_xor(q2, off, 32);
    }
    float m0 = s0 * (1.f / 32.f), m1 = s1 * (1.f / 32.f), m2 = s2 * (1.f / 32.f);
    float var = (q0 * (1.f / 32.f) - m0 * m0) + (q1 * (1.f / 32.f) - m1 * m1) + (q2 * (1.f / 32.f) - m2 * m2);
    float mu = po_b[c] + m0 + m1 + m2;
    float sc = rs_p[0] * rsqrtf(var + 1e-5f);
    p0[t] = v0 * sc; p1[t] = v1 * sc; p2[t] = v2 * sc;
    if (t == 0) sbase = sc * (po_b[c] - mu);
  }
  __syncthreads();
  float basev = sbase;
  const float4* xin = (const float4*)(x + (size_t)bc * 32768);
  float4* xo = (float4*)(out + (size_t)bc * 32768);
  int q0i = half * 4096;
  #pragma unroll 4
  for (int q = q0i + t; q < q0i + 4096; q += 256) {
    int d = q >> 8, h = (q >> 3) & 31, w4 = (q & 7) * 4;
    float add = basev + p0[d] + p1[h];
    float4 v = xin[q];
    v.x += add + p2[w4];
    v.y += add + p2[w4 + 1];
    v.z += add + p2[w4 + 2];
    v.w += add + p2[w4 + 3];
    xo[q] = v;
  }
}

extern "C" void kernel_launch(void* const* d_in, const int* in_sizes, int n_in,
                              void* d_out, int out_size, void* d_ws, size_t ws_size,
                              hipStream_t stream) {
  const float* x      = (const float*)d_in[0];
  const float* ln_w   = (const float*)d_in[1];
  const float* ln_b   = (const float*)d_in[2];
  const float* in_w   = (const float*)d_in[3];
  const float* conv_w = (const float*)d_in[4];
  const float* conv_b = (const float*)d_in[5];
  const float* xp_w   = (const float*)d_in[6];
  const float* dt_w   = (const float*)d_in[7];
  const float* dt_b   = (const float*)d_in[8];
  const float* A_log  = (const float*)d_in[9];
  const float* Dskip  = (const float*)d_in[10];
  const float* out_w  = (const float*)d_in[11];
  const float* up_w   = (const float*)d_in[12];
  const float* up_b   = (const float*)d_in[13];
  const float* Wg_w   = (const float*)d_in[14];
  const float* Wg_b   = (const float*)d_in[15];
  const float* Ws_w   = (const float*)d_in[16];
  const float* Ws_b   = (const float*)d_in[17];
  const float* Wm_w   = (const float*)d_in[18];
  const float* Wm_b   = (const float*)d_in[19];
  const float* po_w   = (const float*)d_in[20];
  const float* po_b   = (const float*)d_in[21];
  const float* rs_p   = (const float*)d_in[22];
  float* out = (float*)d_out;

  float* ws    = (float*)d_ws;
  float* seq   = ws;                 // 36864
  float* xc    = seq   + 36864;      // 73728
  float* zbuf  = xc    + 73728;      // 73728
  float* dbc   = zbuf  + 73728;      // 8448
  float* dt    = dbc   + 8448;       // 73728
  float* y     = dt    + 73728;      // 73728
  float* ymean = y     + 73728;      // 2304
  float* P     = ymean + 2304;       // 36864

  k_reduce <<<dim3(BB * CC),     dim3(1024), 0, stream>>>(x, seq);
  k_convall<<<dim3(3 * BB * 32), dim3(384),  0, stream>>>(seq, ln_w, ln_b, in_w, conv_w, conv_b,
                                                          xp_w, dt_w, dt_b, xc, zbuf, dbc, dt);
  k_scan   <<<dim3(288),         dim3(128),  0, stream>>>(dbc, dt, xc, zbuf, A_log, Dskip, y, ymean);
  k_gate   <<<dim3(3 * BB * 32), dim3(384),  0, stream>>>(y, ymean, out_w, up_w, up_b, Wg_w, Wg_b,
                                                          Ws_w, Ws_b, Wm_w, Wm_b, po_w, P);
  k_final  <<<dim3(BB * CC * 2), dim3(256),  0, stream>>>(x, P, po_b, rs_p, out);
}